// Round 9
// baseline (616.041 us; speedup 1.0000x reference)
//
#include <hip/hip_runtime.h>
#include <hip/hip_bf16.h>

#define NN 50000   // nodes
#define NE 800000  // edges
#define NG 256     // graphs
#define CIN 128
#define CH 256

typedef unsigned short u16;
typedef unsigned int u32;
typedef __attribute__((ext_vector_type(8))) short short8;   // 8 bf16 = 4 VGPRs
typedef __attribute__((ext_vector_type(4))) float f32x4;

__device__ __forceinline__ float bf2f(u16 u) { return __uint_as_float(((u32)u) << 16); }
__device__ __forceinline__ u16 f2bf(float f) {
    u32 u = __float_as_uint(f);
    return (u16)((u + 0x7fffu + ((u >> 16) & 1u)) >> 16);  // RNE
}

// ---------------- init: zero deg/fill + pool ranges ----------------
__global__ void k_init(int* __restrict__ deg_fill, int* __restrict__ gs, int* __restrict__ ge) {
    int i = blockIdx.x * 256 + threadIdx.x;
    if (i < 2 * NN) deg_fill[i] = 0;
    if (i < NG) { gs[i] = 0; ge[i] = 0; }
}

// ---------------- CSR degree count + (merged) pool bounds ----------------
__global__ void k_count_deg_bounds(const int* __restrict__ dst, int* __restrict__ deg,
                                   const int* __restrict__ batch,
                                   int* __restrict__ gs, int* __restrict__ ge) {
    int e = blockIdx.x * 256 + threadIdx.x;
    if (e < NE) atomicAdd(&deg[dst[e]], 1);
    if (e < NN) {  // batch is sorted: boundary detection, no atomics
        int b = batch[e];
        if (e == 0 || batch[e - 1] != b) gs[b] = e;
        if (e == NN - 1 || batch[e + 1] != b) ge[b] = e + 1;
    }
}

__global__ void k_scan1(const int* __restrict__ deg, int* __restrict__ bsum) {
    __shared__ int sd[256];
    int base = blockIdx.x * 1024, t = threadIdx.x, s = 0;
    for (int j = 0; j < 4; j++) { int i = base + t * 4 + j; if (i < NN) s += deg[i]; }
    sd[t] = s; __syncthreads();
    for (int off = 128; off > 0; off >>= 1) { if (t < off) sd[t] += sd[t + off]; __syncthreads(); }
    if (t == 0) bsum[blockIdx.x] = sd[0];
}

// single-wave shuffle scan over nb<=64 block sums
__global__ void k_scan2(int* bsum, int nb, int* row_ptr) {
    int lane = threadIdx.x;
    int v = (lane < nb) ? bsum[lane] : 0;
    int s = v;
    for (int off = 1; off < 64; off <<= 1) {
        int t = __shfl_up(s, off, 64);
        if (lane >= off) s += t;
    }
    if (lane < nb) bsum[lane] = s - v;  // exclusive prefix
    if (lane == 0) row_ptr[NN] = NE;
}

__global__ void k_scan3(const int* __restrict__ deg, const int* __restrict__ bsum,
                        int* __restrict__ row_ptr) {
    __shared__ int sd[256];
    int base = blockIdx.x * 1024, t = threadIdx.x;
    int v[4]; int s = 0;
    for (int j = 0; j < 4; j++) { int i = base + t * 4 + j; v[j] = (i < NN) ? deg[i] : 0; s += v[j]; }
    sd[t] = s; __syncthreads();
    for (int off = 1; off < 256; off <<= 1) {
        int tmp = (t >= off) ? sd[t - off] : 0; __syncthreads();
        sd[t] += tmp; __syncthreads();
    }
    int run = bsum[blockIdx.x] + sd[t] - s;
    for (int j = 0; j < 4; j++) { int i = base + t * 4 + j; if (i < NN) row_ptr[i] = run; run += v[j]; }
}

__global__ void k_fill(const int* __restrict__ src, const int* __restrict__ dst,
                       const int* __restrict__ row_ptr, int* __restrict__ fill,
                       int* __restrict__ col) {
    int e = blockIdx.x * 256 + threadIdx.x;
    if (e < NE) {
        int d = dst[e];
        int pos = row_ptr[d] + atomicAdd(&fill[d], 1);
        col[pos] = src[e];
    }
}

// ---------------- prep: x fp32->bf16 + all weight packs, one dispatch -------
// Wp arena order: w1_0(128x256) | w2_0 | w1s[0..2] | w2s[0..2]  (CHxCH each)
__global__ void k_prep(const float* __restrict__ x, u16* __restrict__ xb,
                       const float* __restrict__ w1_0, const float* __restrict__ w2_0,
                       const float* __restrict__ w1s, const float* __restrict__ w2s,
                       u16* __restrict__ Wp) {
    int t = blockIdx.x * 256 + threadIdx.x;
    if (t < NN * CIN / 4) {
        float4 v = ((const float4*)x)[t];
        ushort4 o; o.x = f2bf(v.x); o.y = f2bf(v.y); o.z = f2bf(v.z); o.w = f2bf(v.w);
        ((ushort4*)xb)[t] = o;
    }
    if (t < CIN * CH + 7 * CH * CH) {
        const float* Wsrc; int rem;
        if (t < CIN * CH) { Wsrc = w1_0; rem = t; }
        else {
            int o = t - CIN * CH;
            int m = o >> 16; rem = o & 65535;  // CH*CH = 65536
            Wsrc = (m == 0) ? w2_0
                 : (m <= 3) ? w1s + (size_t)(m - 1) * 65536
                            : w2s + (size_t)(m - 4) * 65536;
        }
        // Wp[o]: o = ((kb*16+nt)*64+lane)*8+j  <-  W[kb*32+(lane>>4)*8+j][nt*16+(lane&15)]
        int j = rem & 7, lane = (rem >> 3) & 63, nt = (rem >> 9) & 15, kb = rem >> 13;
        int k = kb * 32 + ((lane >> 4) << 3) + j;
        int nc = nt * 16 + (lane & 15);
        Wp[t] = f2bf(Wsrc[k * CH + nc]);
    }
}

// ---------------- aggregation (r7 form: bf16, fp32 accumulate, unroll-8) ----
__global__ void k_agg0_b(const u16* __restrict__ x, const int* __restrict__ row_ptr,
                         const int* __restrict__ col, u16* __restrict__ z) {
    int gid = blockIdx.x * 256 + threadIdx.x;
    int node = gid >> 6, lane = threadIdx.x & 63;
    if (node >= NN) return;
    int c0 = lane * 2;
    ushort2 sv = *(const ushort2*)(x + (size_t)node * CIN + c0);
    float a0 = bf2f(sv.x), a1 = bf2f(sv.y);
    int beg = row_ptr[node], end = row_ptr[node + 1];
    int e = beg;
    for (; e + 8 <= end; e += 8) {
        ushort2 v[8];
#pragma unroll
        for (int q = 0; q < 8; q++) v[q] = *(const ushort2*)(x + (size_t)col[e + q] * CIN + c0);
#pragma unroll
        for (int q = 0; q < 8; q++) { a0 += bf2f(v[q].x); a1 += bf2f(v[q].y); }
    }
    for (; e < end; e++) {
        ushort2 nv = *(const ushort2*)(x + (size_t)col[e] * CIN + c0);
        a0 += bf2f(nv.x); a1 += bf2f(nv.y);
    }
    ushort2 o; o.x = f2bf(a0); o.y = f2bf(a1);
    *(ushort2*)(z + (size_t)node * CIN + c0) = o;
}

__global__ void k_agg_b(const u16* __restrict__ h, const int* __restrict__ row_ptr,
                        const int* __restrict__ col, u16* __restrict__ z) {
    int gid = blockIdx.x * 256 + threadIdx.x;
    int node = gid >> 6, lane = threadIdx.x & 63;
    if (node >= NN) return;
    int c0 = lane * 4;
    ushort4 sv = *(const ushort4*)(h + (size_t)node * CH + c0);
    float a0 = bf2f(sv.x), a1 = bf2f(sv.y), a2 = bf2f(sv.z), a3 = bf2f(sv.w);
    int beg = row_ptr[node], end = row_ptr[node + 1];
    int e = beg;
    for (; e + 8 <= end; e += 8) {
        ushort4 v[8];
#pragma unroll
        for (int q = 0; q < 8; q++) v[q] = *(const ushort4*)(h + (size_t)col[e + q] * CH + c0);
#pragma unroll
        for (int q = 0; q < 8; q++) {
            a0 += bf2f(v[q].x); a1 += bf2f(v[q].y); a2 += bf2f(v[q].z); a3 += bf2f(v[q].w);
        }
    }
    for (; e < end; e++) {
        ushort4 nv = *(const ushort4*)(h + (size_t)col[e] * CH + c0);
        a0 += bf2f(nv.x); a1 += bf2f(nv.y); a2 += bf2f(nv.z); a3 += bf2f(nv.w);
    }
    ushort4 o; o.x = f2bf(a0); o.y = f2bf(a1); o.z = f2bf(a2); o.w = f2bf(a3);
    *(ushort4*)(z + (size_t)node * CH + c0) = o;
}

// ---------------- fused MLP: out = relu(relu(A@W1+b1)@W2+b2) ----------------
// 96-row x 256-col block, 4 waves (wave w owns cols [w*64,w*64+64)).
// Rationale (r8 post-mortem): both big kernels sit on a per-CU VMEM byte-rate
// ceiling (~11 B/cyc/CU); W traffic = nBlocks*256KB, so rows/block is the only
// traffic knob (fusion forces full 256-col blocks). 96 rows: 521 blocks,
// 2.03 blocks/CU balanced, z1 = 50.7 KB LDS (<64 KB static cap).
#define Z1S 264
template <int K1>
__global__ __launch_bounds__(256) void k_mlp(const u16* __restrict__ A,
                                             const u16* __restrict__ Wp1,
                                             const float* __restrict__ b1,
                                             const u16* __restrict__ Wp2,
                                             const float* __restrict__ b2,
                                             u16* __restrict__ out) {
    __shared__ __align__(16) u16 z1[96 * Z1S];  // 50.7 KB
    int tid = threadIdx.x;
    int wave = tid >> 6, lane = tid & 63;
    int quad = lane >> 4, l16 = lane & 15;
    int m0 = blockIdx.x * 96;

    f32x4 acc[6][4];
#pragma unroll
    for (int ri = 0; ri < 6; ri++)
#pragma unroll
        for (int nj = 0; nj < 4; nj++) acc[ri][nj] = (f32x4){0.f, 0.f, 0.f, 0.f};

    int arow[6];
#pragma unroll
    for (int ri = 0; ri < 6; ri++) {
        int r = m0 + ri * 16 + l16;
        arow[ri] = (r < NN) ? r : (NN - 1);
    }

    const u16* w1b = Wp1 + (wave * 4) * 512 + lane * 8;
    const u16* w2b = Wp2 + (wave * 4) * 512 + lane * 8;

    // ---- GEMM1 (K=K1): b-frags prefetched 1-deep; a-frags 6-way ILP ----
    const int KB1 = K1 / 32;
    short8 b_cur[4], b_nxt[4];
#pragma unroll
    for (int nj = 0; nj < 4; nj++) b_cur[nj] = *(const short8*)(w1b + nj * 512);

#pragma unroll
    for (int kb = 0; kb < KB1; kb++) {
        int kn = (kb + 1 < KB1) ? (kb + 1) : kb;
#pragma unroll
        for (int nj = 0; nj < 4; nj++)
            b_nxt[nj] = *(const short8*)(w1b + kn * 8192 + nj * 512);
        short8 a[6];
        int ka = kb * 32 + quad * 8;
#pragma unroll
        for (int ri = 0; ri < 6; ri++)
            a[ri] = *(const short8*)(A + (size_t)arow[ri] * K1 + ka);
#pragma unroll
        for (int nj = 0; nj < 4; nj++)
#pragma unroll
            for (int ri = 0; ri < 6; ri++)
                acc[ri][nj] = __builtin_amdgcn_mfma_f32_16x16x32_bf16(a[ri], b_cur[nj], acc[ri][nj], 0, 0, 0);
#pragma unroll
        for (int nj = 0; nj < 4; nj++) b_cur[nj] = b_nxt[nj];
    }

    // ---- bias1 + relu -> z1 ----
#pragma unroll
    for (int nj = 0; nj < 4; nj++) {
        int cc = wave * 64 + nj * 16 + l16;
        float bv = b1[cc];
#pragma unroll
        for (int ri = 0; ri < 6; ri++) {
            f32x4 v = acc[ri][nj];
#pragma unroll
            for (int j = 0; j < 4; j++)
                z1[(ri * 16 + quad * 4 + j) * Z1S + cc] = f2bf(fmaxf(v[j] + bv, 0.f));
        }
    }
    __syncthreads();

    // ---- GEMM2 (K=256): a from LDS, b prefetched ----
#pragma unroll
    for (int ri = 0; ri < 6; ri++)
#pragma unroll
        for (int nj = 0; nj < 4; nj++) acc[ri][nj] = (f32x4){0.f, 0.f, 0.f, 0.f};

#pragma unroll
    for (int nj = 0; nj < 4; nj++) b_cur[nj] = *(const short8*)(w2b + nj * 512);

#pragma unroll
    for (int kb = 0; kb < 8; kb++) {
        int kn = (kb + 1 < 8) ? (kb + 1) : kb;
#pragma unroll
        for (int nj = 0; nj < 4; nj++)
            b_nxt[nj] = *(const short8*)(w2b + kn * 8192 + nj * 512);
        short8 a[6];
#pragma unroll
        for (int ri = 0; ri < 6; ri++)
            a[ri] = *(const short8*)(z1 + (ri * 16 + l16) * Z1S + kb * 32 + quad * 8);
#pragma unroll
        for (int nj = 0; nj < 4; nj++)
#pragma unroll
            for (int ri = 0; ri < 6; ri++)
                acc[ri][nj] = __builtin_amdgcn_mfma_f32_16x16x32_bf16(a[ri], b_cur[nj], acc[ri][nj], 0, 0, 0);
#pragma unroll
        for (int nj = 0; nj < 4; nj++) b_cur[nj] = b_nxt[nj];
    }
    __syncthreads();  // z1 reads done before overwrite

    // ---- bias2 + relu -> z1, then coalesced 16B stores ----
#pragma unroll
    for (int nj = 0; nj < 4; nj++) {
        int cc = wave * 64 + nj * 16 + l16;
        float bv = b2[cc];
#pragma unroll
        for (int ri = 0; ri < 6; ri++) {
            f32x4 v = acc[ri][nj];
#pragma unroll
            for (int j = 0; j < 4; j++)
                z1[(ri * 16 + quad * 4 + j) * Z1S + cc] = f2bf(fmaxf(v[j] + bv, 0.f));
        }
    }
    __syncthreads();

    // 96 rows x 512 B; threads 0..191 store one half-row (256 B) each
    if (tid < 192) {
        int row = tid >> 1, cb = (tid & 1) * 128;
        if (m0 + row < NN) {
            uint4* dst = (uint4*)(out + (size_t)(m0 + row) * CH + cb);
            const u16* srcp = z1 + row * Z1S + cb;
#pragma unroll
            for (int c = 0; c < 16; c++) dst[c] = *(const uint4*)(srcp + c * 8);
        }
    }
}

// ---------------- global_add_pool ----------------
__global__ void k_pool(const u16* __restrict__ h, const int* __restrict__ gs,
                       const int* __restrict__ ge, float* __restrict__ out) {
    int g = blockIdx.x, c = threadIdx.x;
    int s = gs[g], e = ge[g];
    float acc = 0.f;
    for (int i = s; i < e; i++) acc += bf2f(h[(size_t)i * CH + c]);
    out[g * CH + c] = acc;
}

extern "C" void kernel_launch(void* const* d_in, const int* in_sizes, int n_in,
                              void* d_out, int out_size, void* d_ws, size_t ws_size,
                              hipStream_t stream) {
    const float* x     = (const float*)d_in[0];
    const int*   ei    = (const int*)d_in[1];
    const int*   batch = (const int*)d_in[2];
    const float* w1_0  = (const float*)d_in[3];
    const float* b1_0  = (const float*)d_in[4];
    const float* w2_0  = (const float*)d_in[5];
    const float* b2_0  = (const float*)d_in[6];
    const float* w1s   = (const float*)d_in[7];
    const float* b1s   = (const float*)d_in[8];
    const float* w2s   = (const float*)d_in[9];
    const float* b2s   = (const float*)d_in[10];
    float* out = (float*)d_out;

    char* p = (char*)d_ws;
    u16* Hb  = (u16*)p; p += (size_t)NN * CH * 2;
    u16* Tb  = (u16*)p; p += (size_t)NN * CH * 2;
    u16* T0b = (u16*)p; p += (size_t)NN * CIN * 2;
    u16* xb  = (u16*)p; p += (size_t)NN * CIN * 2;
    u16* WpA = (u16*)p; p += (size_t)(CIN * CH + 7 * CH * CH) * 2;  // 1+7 packed mats
    int* row_ptr = (int*)p; p += (size_t)(NN + 1) * 4;
    int* deg  = (int*)p; p += (size_t)NN * 4;
    int* fill = (int*)p; p += (size_t)NN * 4;   // adjacent to deg (zeroed together)
    int* col  = (int*)p; p += (size_t)NE * 4;
    int* bsum = (int*)p; p += 64 * 4;
    int* gs   = (int*)p; p += NG * 4;
    int* ge   = (int*)p; p += NG * 4;

    u16* Wp1_0 = WpA;                          // 128x256
    u16* Wp2_0 = Wp1_0 + CIN * CH;             // 256x256
    u16* Wp1sA = Wp2_0 + CH * CH;              // 3 x 256x256
    u16* Wp2sA = Wp1sA + 3 * CH * CH;          // 3 x 256x256

    const int* srcv = ei;
    const int* dstv = ei + NE;

    int nb = (NN + 1023) / 1024;  // 49
    hipLaunchKernelGGL(k_init, dim3((2 * NN + 255) / 256), dim3(256), 0, stream, deg, gs, ge);
    hipLaunchKernelGGL(k_count_deg_bounds, dim3((NE + 255) / 256), dim3(256), 0, stream,
                       dstv, deg, batch, gs, ge);
    hipLaunchKernelGGL(k_scan1, dim3(nb), dim3(256), 0, stream, deg, bsum);
    hipLaunchKernelGGL(k_scan2, dim3(1), dim3(64), 0, stream, bsum, nb, row_ptr);
    hipLaunchKernelGGL(k_scan3, dim3(nb), dim3(256), 0, stream, deg, bsum, row_ptr);
    hipLaunchKernelGGL(k_fill, dim3((NE + 255) / 256), dim3(256), 0, stream, srcv, dstv, row_ptr, fill, col);
    hipLaunchKernelGGL(k_prep, dim3((NN * CIN / 4 + 255) / 256), dim3(256), 0, stream,
                       x, xb, w1_0, w2_0, w1s, w2s, WpA);

    int aggBlocks = (NN * 64 + 255) / 256;  // 12500
    int mlpBlocks = (NN + 95) / 96;         // 521

    // layer 0: xb -> T0b -> Hb
    hipLaunchKernelGGL(k_agg0_b, dim3(aggBlocks), dim3(256), 0, stream, xb, row_ptr, col, T0b);
    hipLaunchKernelGGL((k_mlp<128>), dim3(mlpBlocks), dim3(256), 0, stream,
                       T0b, Wp1_0, b1_0, Wp2_0, b2_0, Hb);

    // layers 1..3: Hb -> Tb -> Hb
    for (int l = 0; l < 3; l++) {
        hipLaunchKernelGGL(k_agg_b, dim3(aggBlocks), dim3(256), 0, stream, Hb, row_ptr, col, Tb);
        hipLaunchKernelGGL((k_mlp<256>), dim3(mlpBlocks), dim3(256), 0, stream,
                           Tb, Wp1sA + (size_t)l * CH * CH, b1s + (size_t)l * CH,
                           Wp2sA + (size_t)l * CH * CH, b2s + (size_t)l * CH, Hb);
    }

    hipLaunchKernelGGL(k_pool, dim3(NG), dim3(256), 0, stream, Hb, gs, ge, out);
}